// Round 1
// baseline (963.846 us; speedup 1.0000x reference)
//
#include <hip/hip_runtime.h>
#include <cstdint>
#include <cstddef>

#define NN 200000
#define DD 128
#define II 4      // I+1
#define PP 64
#define QQ 100
#define GG 1000

// ---------------------------------------------------------------------------
// starts[g] = first index with batch[idx] >= g  (batch is sorted); starts[G]=N
// ---------------------------------------------------------------------------
__global__ void starts_kernel(const int* __restrict__ batch, int* __restrict__ starts) {
    int g = blockIdx.x * blockDim.x + threadIdx.x;
    if (g > GG) return;
    if (g == GG) { starts[g] = NN; return; }
    int lo = 0, hi = NN;
    while (lo < hi) {
        int mid = (lo + hi) >> 1;
        if (batch[mid] < g) lo = mid + 1; else hi = mid;
    }
    starts[g] = lo;
}

// ---------------------------------------------------------------------------
// Projection for one WL-slice i: xp_i[p][n] = sum_d x[n][i*128+d] * proj[d][p]
// Block: 256 thr, 64 n-rows. Wave w computes p = w*16..w*16+15 for n = lane.
// x tile staged in LDS (stride 129 -> 2-way bank alias = free).
// proj reads are wave-uniform -> scalar loads.
// ---------------------------------------------------------------------------
__global__ __launch_bounds__(256) void proj_kernel(
        const float* __restrict__ x, const float* __restrict__ proj,
        float* __restrict__ xp_i, int i) {
    __shared__ float xs[64 * 129];
    const int t    = threadIdx.x;
    const int n0   = blockIdx.x * 64;
    const int lane = t & 63;
    const int pg   = __builtin_amdgcn_readfirstlane(t >> 6);  // wave id 0..3

    // load 64 rows x 128 cols of x for this slice
    {
        const int c4 = t & 31;     // float4 column
        const int r0 = t >> 5;     // 0..7
        #pragma unroll
        for (int pass = 0; pass < 8; ++pass) {
            const int row = r0 + pass * 8;
            const float4 v = *(const float4*)(x + (size_t)(n0 + row) * 512 + i * 128 + c4 * 4);
            float* dst = xs + row * 129 + c4 * 4;
            dst[0] = v.x; dst[1] = v.y; dst[2] = v.z; dst[3] = v.w;
        }
    }
    __syncthreads();

    float acc[16];
    #pragma unroll
    for (int pp = 0; pp < 16; ++pp) acc[pp] = 0.f;

    const float* __restrict__ pbase = proj + pg * 16;   // uniform -> s_load
    const float* __restrict__ xrow  = xs + lane * 129;
    #pragma unroll 4
    for (int d = 0; d < 128; ++d) {
        const float xv = xrow[d];
        #pragma unroll
        for (int pp = 0; pp < 16; ++pp)
            acc[pp] += xv * pbase[d * 64 + pp];
    }

    #pragma unroll
    for (int pp = 0; pp < 16; ++pp)
        xp_i[(size_t)(pg * 16 + pp) * NN + n0 + lane] = acc[pp];  // 256B coalesced
}

// ---------------------------------------------------------------------------
// Register bitonic sort across one wave. Element e = lane*VPT + r.
// j <  VPT : in-register compare-exchange
// j >= VPT : cross-lane via shfl_xor(lane distance j/VPT)
// ---------------------------------------------------------------------------
template<int VPT>
__device__ inline void bitonic_sort(float v[VPT], int lane) {
    constexpr int NS = VPT * 64;
    #pragma unroll
    for (int k = 2; k <= NS; k <<= 1) {
        #pragma unroll
        for (int j = k >> 1; j >= 1; j >>= 1) {
            if (j >= VPT) {
                const int  d        = j / VPT;
                const bool up       = ((lane * VPT) & k) == 0;
                const bool lower    = (lane & d) == 0;
                const bool keep_min = (up == lower);
                #pragma unroll
                for (int r = 0; r < VPT; ++r) {
                    const float pv = __shfl_xor(v[r], d);
                    const float mn = fminf(v[r], pv);
                    const float mx = fmaxf(v[r], pv);
                    v[r] = keep_min ? mn : mx;
                }
            } else {
                #pragma unroll
                for (int r = 0; r < VPT; ++r) {
                    if ((r & j) == 0) {
                        const int  r2 = r | j;
                        const bool up = (((lane * VPT + r) & k) == 0);
                        const float a = v[r], b = v[r2];
                        const float mn = fminf(a, b), mx = fmaxf(a, b);
                        v[r]  = up ? mn : mx;
                        v[r2] = up ? mx : mn;
                    }
                }
            }
        }
    }
}

// ---------------------------------------------------------------------------
// One block (1024 thr, 16 waves) = (g, pq): 16 columns p = pq*16 + w of one
// (g, i). Each wave register-sorts its column segment, stages the sorted run
// in LDS, then all threads cooperatively gather the 100 quantiles with
// 64B-contiguous stores.
// ---------------------------------------------------------------------------
__global__ __launch_bounds__(1024) void sort_quant_kernel(
        const float* __restrict__ xp_i, const int* __restrict__ starts,
        const float* __restrict__ cw, float* __restrict__ out, int i) {
    __shared__ float sbuf[16 * 513];
    const int b    = blockIdx.x;       // g*4 + pq
    const int g    = b >> 2;
    const int pq   = b & 3;
    const int t    = threadIdx.x;
    const int w    = __builtin_amdgcn_readfirstlane(t >> 6);  // wave 0..15
    const int lane = t & 63;

    const int start = starts[g];
    const int cnt   = starts[g + 1] - start;

    const int col = pq * 16 + w;                       // p within slice
    const float* __restrict__ src = xp_i + (size_t)col * NN + start;
    float* lrow = sbuf + w * 513;

    if (cnt <= 256) {
        float v[4];
        #pragma unroll
        for (int r = 0; r < 4; ++r) {
            const int e = lane * 4 + r;
            v[r] = (e < cnt) ? src[e] : __builtin_inff();
        }
        bitonic_sort<4>(v, lane);
        #pragma unroll
        for (int r = 0; r < 4; ++r) lrow[lane * 4 + r] = v[r];
    } else {
        float v[8];
        #pragma unroll
        for (int r = 0; r < 8; ++r) {
            const int e = lane * 8 + r;
            v[r] = (e < cnt && e < 512) ? src[e] : __builtin_inff();
        }
        bitonic_sort<8>(v, lane);
        #pragma unroll
        for (int r = 0; r < 8; ++r) lrow[lane * 8 + r] = v[r];
    }
    __syncthreads();

    // quantile extraction: thread t -> (pl = t&15, qt = t>>4)
    const float cm1 = (float)(cnt > 0 ? cnt - 1 : 0);
    const int   pl  = t & 15;
    const int   qt  = t >> 4;           // 0..63
    const float inv_scale = 1.0f / 80.0f;   // (Q*P)^(-1/POW) = 1/80
    float* __restrict__ orow = out + (size_t)g * 25600 + i * 6400 + pq * 16 + pl;

    {
        const int q  = qt;
        int tq = (int)floorf(cw[q] * cm1);
        if (tq > 511) tq = 511;
        orow[q * 64] = sbuf[pl * 513 + tq] * inv_scale;
    }
    if (qt < QQ - 64) {
        const int q  = 64 + qt;
        int tq = (int)floorf(cw[q] * cm1);
        if (tq > 511) tq = 511;
        orow[q * 64] = sbuf[pl * 513 + tq] * inv_scale;
    }
}

// ---------------------------------------------------------------------------
extern "C" void kernel_launch(void* const* d_in, const int* in_sizes, int n_in,
                              void* d_out, int out_size, void* d_ws, size_t ws_size,
                              hipStream_t stream) {
    const float* x     = (const float*)d_in[0];   // [N, 4*128]
    const int*   batch = (const int*)  d_in[1];   // [N]
    const float* proj  = (const float*)d_in[2];   // [128, 64]
    const float* cw    = (const float*)d_in[3];   // [100]
    float*       out   = (float*)d_out;           // [1000, 25600]

    int*   starts = (int*)d_ws;                               // 1001 ints
    float* xp_i   = (float*)((char*)d_ws + 4096);             // 64*N floats (51.2MB)

    starts_kernel<<<4, 256, 0, stream>>>(batch, starts);

    for (int i = 0; i < II; ++i) {
        proj_kernel<<<NN / 64, 256, 0, stream>>>(x, proj, xp_i, i);
        sort_quant_kernel<<<GG * 4, 1024, 0, stream>>>(xp_i, starts, cw, out, i);
    }
}

// Round 2
// 894.718 us; speedup vs baseline: 1.0773x; 1.0773x over previous
//
#include <hip/hip_runtime.h>
#include <cstdint>
#include <cstddef>

#define NN 200000
#define DD 128
#define II 4      // I+1
#define PP 64
#define QQ 100
#define GG 1000

// ---------------------------------------------------------------------------
// starts[g] = first index with batch[idx] >= g  (batch is sorted); starts[G]=N
// ---------------------------------------------------------------------------
__global__ void starts_kernel(const int* __restrict__ batch, int* __restrict__ starts) {
    int g = blockIdx.x * blockDim.x + threadIdx.x;
    if (g > GG) return;
    if (g == GG) { starts[g] = NN; return; }
    int lo = 0, hi = NN;
    while (lo < hi) {
        int mid = (lo + hi) >> 1;
        if (batch[mid] < g) lo = mid + 1; else hi = mid;
    }
    starts[g] = lo;
}

// ---------------------------------------------------------------------------
// Projection, all slices in one dispatch: blockIdx.y = i (0..3).
// xp[i*64+p][n] = sum_d x[n][i*128+d] * proj[d][p]
// Block: 256 thr, 64 n-rows. Wave w computes p = w*16..w*16+15 for n = lane.
// x tile staged in LDS, stride 132 so rows are 16B-aligned -> ds_read_b128;
// chunk index (lane + d4) % 8 covers all chunks evenly -> conflict-free.
// proj reads are wave-uniform -> scalar loads through constant cache.
// ---------------------------------------------------------------------------
__global__ __launch_bounds__(256) void proj_kernel(
        const float* __restrict__ x, const float* __restrict__ proj,
        float* __restrict__ xp) {
    __shared__ float xs[64 * 132];
    const int t    = threadIdx.x;
    const int n0   = blockIdx.x * 64;
    const int i    = blockIdx.y;
    const int lane = t & 63;
    const int pg   = __builtin_amdgcn_readfirstlane(t >> 6);  // wave id 0..3

    // stage 64 rows x 128 cols of x-slice i into LDS (float4 in/out)
    {
        const int c4 = t & 31;     // float4 column 0..31
        const int r0 = t >> 5;     // 0..7
        #pragma unroll
        for (int pass = 0; pass < 8; ++pass) {
            const int row = r0 + pass * 8;
            const float4 v = *(const float4*)(x + (size_t)(n0 + row) * 512 + i * 128 + c4 * 4);
            *(float4*)(xs + row * 132 + c4 * 4) = v;
        }
    }
    __syncthreads();

    float acc[16];
    #pragma unroll
    for (int pp = 0; pp < 16; ++pp) acc[pp] = 0.f;

    const float* __restrict__ pbase = proj + pg * 16;   // uniform -> s_load
    const float* __restrict__ xrow  = xs + lane * 132;

    #pragma unroll 4
    for (int d4 = 0; d4 < 32; ++d4) {
        const float4 xv = *(const float4*)(xrow + d4 * 4);
        #pragma unroll
        for (int pp = 0; pp < 16; ++pp) acc[pp] += xv.x * pbase[(d4 * 4 + 0) * 64 + pp];
        #pragma unroll
        for (int pp = 0; pp < 16; ++pp) acc[pp] += xv.y * pbase[(d4 * 4 + 1) * 64 + pp];
        #pragma unroll
        for (int pp = 0; pp < 16; ++pp) acc[pp] += xv.z * pbase[(d4 * 4 + 2) * 64 + pp];
        #pragma unroll
        for (int pp = 0; pp < 16; ++pp) acc[pp] += xv.w * pbase[(d4 * 4 + 3) * 64 + pp];
    }

    float* __restrict__ obase = xp + ((size_t)i * 64 + pg * 16) * NN + n0 + lane;
    #pragma unroll
    for (int pp = 0; pp < 16; ++pp)
        obase[(size_t)pp * NN] = acc[pp];   // 256B coalesced per store
}

// ---------------------------------------------------------------------------
// Register bitonic sort across one wave. Element e = lane*VPT + r.
// ---------------------------------------------------------------------------
template<int VPT>
__device__ inline void bitonic_sort(float v[VPT], int lane) {
    constexpr int NS = VPT * 64;
    #pragma unroll
    for (int k = 2; k <= NS; k <<= 1) {
        #pragma unroll
        for (int j = k >> 1; j >= 1; j >>= 1) {
            if (j >= VPT) {
                const int  d        = j / VPT;
                const bool up       = ((lane * VPT) & k) == 0;
                const bool lower    = (lane & d) == 0;
                const bool keep_min = (up == lower);
                #pragma unroll
                for (int r = 0; r < VPT; ++r) {
                    const float pv = __shfl_xor(v[r], d);
                    const float mn = fminf(v[r], pv);
                    const float mx = fmaxf(v[r], pv);
                    v[r] = keep_min ? mn : mx;
                }
            } else {
                #pragma unroll
                for (int r = 0; r < VPT; ++r) {
                    if ((r & j) == 0) {
                        const int  r2 = r | j;
                        const bool up = (((lane * VPT + r) & k) == 0);
                        const float a = v[r], b = v[r2];
                        const float mn = fminf(a, b), mx = fmaxf(a, b);
                        v[r]  = up ? mn : mx;
                        v[r2] = up ? mx : mn;
                    }
                }
            }
        }
    }
}

// ---------------------------------------------------------------------------
// One block (512 thr, 8 waves) = (g, pq, i): 8 columns p = pq*8 + w of slice
// i. Each wave register-sorts its column segment, stages the sorted run in
// LDS, then all threads cooperatively gather the 100 quantiles.
// grid: (GG*8, 4)
// ---------------------------------------------------------------------------
__global__ __launch_bounds__(512) void sort_quant_kernel(
        const float* __restrict__ xp, const int* __restrict__ starts,
        const float* __restrict__ cw, float* __restrict__ out) {
    __shared__ float sbuf[8 * 513];
    const int b    = blockIdx.x;       // g*8 + pq
    const int g    = b >> 3;
    const int pq   = b & 7;
    const int i    = blockIdx.y;
    const int t    = threadIdx.x;
    const int w    = __builtin_amdgcn_readfirstlane(t >> 6);  // wave 0..7
    const int lane = t & 63;

    const int start = starts[g];
    const int cnt   = starts[g + 1] - start;

    const int col = pq * 8 + w;                        // p within slice
    const float* __restrict__ src = xp + ((size_t)i * 64 + col) * NN + start;
    float* lrow = sbuf + w * 513;

    if (cnt <= 256) {
        float v[4];
        #pragma unroll
        for (int r = 0; r < 4; ++r) {
            const int e = lane * 4 + r;
            v[r] = (e < cnt) ? src[e] : __builtin_inff();
        }
        bitonic_sort<4>(v, lane);
        #pragma unroll
        for (int r = 0; r < 4; ++r) lrow[lane * 4 + r] = v[r];
    } else {
        float v[8];
        #pragma unroll
        for (int r = 0; r < 8; ++r) {
            const int e = lane * 8 + r;
            v[r] = (e < cnt && e < 512) ? src[e] : __builtin_inff();
        }
        bitonic_sort<8>(v, lane);
        #pragma unroll
        for (int r = 0; r < 8; ++r) lrow[lane * 8 + r] = v[r];
    }
    __syncthreads();

    // quantile extraction: thread t -> (pl = t&7, qt = t>>3)
    const float cm1 = (float)(cnt > 0 ? cnt - 1 : 0);
    const int   pl  = t & 7;
    const int   qt  = t >> 3;           // 0..63
    const float inv_scale = 1.0f / 80.0f;   // (Q*P)^(-1/POW) = 1/80
    float* __restrict__ orow = out + (size_t)g * 25600 + i * 6400 + pq * 8 + pl;

    {
        const int q  = qt;
        int tq = (int)floorf(cw[q] * cm1);
        if (tq > 511) tq = 511;
        orow[q * 64] = sbuf[pl * 513 + tq] * inv_scale;
    }
    if (qt < QQ - 64) {
        const int q  = 64 + qt;
        int tq = (int)floorf(cw[q] * cm1);
        if (tq > 511) tq = 511;
        orow[q * 64] = sbuf[pl * 513 + tq] * inv_scale;
    }
}

// ---------------------------------------------------------------------------
extern "C" void kernel_launch(void* const* d_in, const int* in_sizes, int n_in,
                              void* d_out, int out_size, void* d_ws, size_t ws_size,
                              hipStream_t stream) {
    const float* x     = (const float*)d_in[0];   // [N, 4*128]
    const int*   batch = (const int*)  d_in[1];   // [N]
    const float* proj  = (const float*)d_in[2];   // [128, 64]
    const float* cw    = (const float*)d_in[3];   // [100]
    float*       out   = (float*)d_out;           // [1000, 25600]

    int*   starts = (int*)d_ws;                               // 1001 ints
    float* xp     = (float*)((char*)d_ws + 4096);             // 4*64*N floats (204.8MB)

    starts_kernel<<<4, 256, 0, stream>>>(batch, starts);
    proj_kernel<<<dim3(NN / 64, II), 256, 0, stream>>>(x, proj, xp);
    sort_quant_kernel<<<dim3(GG * 8, II), 512, 0, stream>>>(xp, starts, cw, out);
}